// Round 3
// baseline (191.071 us; speedup 1.0000x reference)
//
#include <hip/hip_runtime.h>
#include <hip/hip_bf16.h>

#define N 16384
#define TPB 256
#define QPT 4
#define QTILE (TPB * QPT)        // 1024 queries per block
#define NQT (N / QTILE)          // 16 query tiles
#define SPLIT 32                 // ref-chunks per direction
#define CHUNK (N / SPLIT)        // 512 refs per chunk
#define GRID (2 * SPLIT * NQT)   // 1024 blocks
#define INF_BITS 0x7F800000

// ws layout: [0, 2N) float4 packed {x,y,z,|r|^2}; [2N) ints minbuf; 1 int counter
__global__ void pack_kernel(const float* __restrict__ p_hat,
                            const float* __restrict__ p,
                            float4* __restrict__ q4,
                            int* __restrict__ minbuf,
                            int* __restrict__ counter) {
    int idx = blockIdx.x * blockDim.x + threadIdx.x;
    if (idx == 0) *counter = 0;
    if (idx >= 2 * N) return;
    const float* src = (idx < N) ? p_hat : p;
    int k = (idx < N) ? idx : idx - N;
    float x = src[3 * k + 0], y = src[3 * k + 1], z = src[3 * k + 2];
    q4[idx] = make_float4(x, y, z, x * x + y * y + z * z);
    minbuf[idx] = INF_BITS;
}

__global__ void __launch_bounds__(TPB) chamfer_kernel(const float4* __restrict__ q4,
                                                      int* __restrict__ minbuf,
                                                      int* __restrict__ counter,
                                                      float* __restrict__ out) {
    int b    = blockIdx.x;
    int dir  = b & 1;
    int rest = b >> 1;
    int jc   = rest & (SPLIT - 1);
    int qt   = rest / SPLIT;

    const float4* __restrict__ qp = q4 + (dir ? N : 0); // queries
    const float4* __restrict__ rp = q4 + (dir ? 0 : N); // references

    int ibase = qt * QTILE + (int)threadIdx.x;
    float m2x[QPT], m2y[QPT], m2z[QPT], qw[QPT], vmin[QPT];
#pragma unroll
    for (int q = 0; q < QPT; ++q) {
        float4 qq = qp[ibase + q * TPB];
        m2x[q] = -2.0f * qq.x; m2y[q] = -2.0f * qq.y; m2z[q] = -2.0f * qq.z;
        qw[q] = qq.w;
        vmin[q] = __builtin_inff();
    }

    int j0 = jc * CHUNK;
#pragma unroll 4
    for (int j = j0; j < j0 + CHUNK; j += 2) {
        float4 ra = rp[j];       // wave-uniform -> s_load
        float4 rb = rp[j + 1];
#pragma unroll
        for (int q = 0; q < QPT; ++q) {
            float ta = __builtin_fmaf(ra.x, m2x[q],
                       __builtin_fmaf(ra.y, m2y[q],
                       __builtin_fmaf(ra.z, m2z[q], ra.w)));
            float tb = __builtin_fmaf(rb.x, m2x[q],
                       __builtin_fmaf(rb.y, m2y[q],
                       __builtin_fmaf(rb.z, m2z[q], rb.w)));
            vmin[q] = fminf(vmin[q], fminf(ta, tb)); // -> v_min3_f32
        }
    }

#pragma unroll
    for (int q = 0; q < QPT; ++q) {
        float m = fmaxf(vmin[q] + qw[q], 0.0f);
        atomicMin(&minbuf[dir * N + ibase + q * TPB], __float_as_int(m));
    }

    // ---- last-finishing block performs the final reduction ----
    __threadfence();
    __shared__ int lastFlag;
    __syncthreads(); // drain all waves' atomics before taking a ticket
    if (threadIdx.x == 0) {
        int prev = __hip_atomic_fetch_add(counter, 1, __ATOMIC_ACQ_REL,
                                          __HIP_MEMORY_SCOPE_AGENT);
        lastFlag = (prev == GRID - 1);
    }
    __syncthreads();
    if (!lastFlag) return;

    float s = 0.0f;
    for (int k = threadIdx.x; k < 2 * N; k += TPB) {
        int v = __hip_atomic_load(&minbuf[k], __ATOMIC_RELAXED,
                                  __HIP_MEMORY_SCOPE_AGENT);
        s += __int_as_float(v);
    }
    for (int off = 32; off > 0; off >>= 1) s += __shfl_down(s, off, 64);
    __shared__ float partial[TPB / 64];
    int lane = threadIdx.x & 63;
    int wid  = threadIdx.x >> 6;
    if (lane == 0) partial[wid] = s;
    __syncthreads();
    if (threadIdx.x == 0) {
        float t = 0.0f;
        for (int w = 0; w < TPB / 64; ++w) t += partial[w];
        out[0] = t / (float)N;
    }
}

extern "C" void kernel_launch(void* const* d_in, const int* in_sizes, int n_in,
                              void* d_out, int out_size, void* d_ws, size_t ws_size,
                              hipStream_t stream) {
    const float* p_hat = (const float*)d_in[0];
    const float* p     = (const float*)d_in[1];
    float4* q4      = (float4*)d_ws;
    int*    minbuf  = (int*)((char*)d_ws + 2 * N * sizeof(float4));
    int*    counter = minbuf + 2 * N;
    float*  out     = (float*)d_out;

    pack_kernel<<<(2 * N + TPB - 1) / TPB, TPB, 0, stream>>>(p_hat, p, q4, minbuf, counter);
    chamfer_kernel<<<GRID, TPB, 0, stream>>>(q4, minbuf, counter, out);
}

// Round 4
// 113.644 us; speedup vs baseline: 1.6813x; 1.6813x over previous
//
#include <hip/hip_runtime.h>
#include <hip/hip_bf16.h>

#define N 16384
#define TPB 256
#define SPLIT 32           // ref-chunks per direction
#define CHUNK (N / SPLIT)  // 512 refs per block
#define QPT 2              // queries per thread
#define QTILE (TPB * QPT)  // 512 queries per block
#define INF_BITS 0x7F800000

// ws layout: [0, 2N) float4 packed points {x,y,z,|r|^2}; then [2N) ints minbuf
__global__ void pack_kernel(const float* __restrict__ p_hat,
                            const float* __restrict__ p,
                            float4* __restrict__ q4,
                            int* __restrict__ minbuf) {
    int idx = blockIdx.x * blockDim.x + threadIdx.x;
    if (idx >= 2 * N) return;
    const float* src = (idx < N) ? p_hat : p;
    int k = (idx < N) ? idx : idx - N;
    float x = src[3 * k + 0], y = src[3 * k + 1], z = src[3 * k + 2];
    q4[idx] = make_float4(x, y, z, x * x + y * y + z * z);
    minbuf[idx] = INF_BITS;
}

// ---- main: per 2 refs x query: 6 fma + 1 min3 (+1 shared mov) ----
// grid: 2 dirs x SPLIT x (N/QTILE) = 2048 blocks
__global__ void __launch_bounds__(TPB) chamfer_kernel(const float4* __restrict__ q4,
                                                      int* __restrict__ minbuf) {
    int b    = blockIdx.x;
    int dir  = b & 1;
    int rest = b >> 1;
    int jc   = rest & (SPLIT - 1);
    int qt   = rest / SPLIT;

    const float4* __restrict__ qp = q4 + (dir ? N : 0); // queries
    const float4* __restrict__ rp = q4 + (dir ? 0 : N); // references

    int i0 = qt * QTILE + (int)threadIdx.x;
    int i1 = i0 + TPB;
    float4 q0 = qp[i0];
    float4 q1 = qp[i1];
    float m2x0 = -2.0f * q0.x, m2y0 = -2.0f * q0.y, m2z0 = -2.0f * q0.z;
    float m2x1 = -2.0f * q1.x, m2y1 = -2.0f * q1.y, m2z1 = -2.0f * q1.z;

    float vmin0 = __builtin_inff();
    float vmin1 = __builtin_inff();

    int j0 = jc * CHUNK;
#pragma unroll 4
    for (int j = j0; j < j0 + CHUNK; j += 2) {
        float4 ra = rp[j];       // wave-uniform -> s_load_dwordx4
        float4 rb = rp[j + 1];
        float ta0 = __builtin_fmaf(ra.x, m2x0,
                    __builtin_fmaf(ra.y, m2y0,
                    __builtin_fmaf(ra.z, m2z0, ra.w)));
        float tb0 = __builtin_fmaf(rb.x, m2x0,
                    __builtin_fmaf(rb.y, m2y0,
                    __builtin_fmaf(rb.z, m2z0, rb.w)));
        // raw min3: inputs are finite (no NaN possible) -> skip IEEE canonicalization
        asm("v_min3_f32 %0, %0, %1, %2" : "+v"(vmin0) : "v"(ta0), "v"(tb0));
        float ta1 = __builtin_fmaf(ra.x, m2x1,
                    __builtin_fmaf(ra.y, m2y1,
                    __builtin_fmaf(ra.z, m2z1, ra.w)));
        float tb1 = __builtin_fmaf(rb.x, m2x1,
                    __builtin_fmaf(rb.y, m2y1,
                    __builtin_fmaf(rb.z, m2z1, rb.w)));
        asm("v_min3_f32 %0, %0, %1, %2" : "+v"(vmin1) : "v"(ta1), "v"(tb1));
    }
    // d^2 = |q|^2 + (|r|^2 - 2 q.r); clamp to 0 (monotone, commutes with min)
    float m0 = fmaxf(vmin0 + q0.w, 0.0f);
    float m1 = fmaxf(vmin1 + q1.w, 0.0f);
    atomicMin(&minbuf[dir * N + i0], __float_as_int(m0));
    atomicMin(&minbuf[dir * N + i1], __float_as_int(m1));
}

// ---- reduce: out = sum(all 2N mins) / N ----
__global__ void __launch_bounds__(1024) reduce_kernel(const int* __restrict__ minbuf,
                                                      float* __restrict__ out) {
    const int4* mb4 = (const int4*)minbuf;  // 2N/4 = 8192 int4
    float s = 0.0f;
#pragma unroll
    for (int k = 0; k < (2 * N / 4) / 1024; ++k) {
        int4 v = mb4[k * 1024 + threadIdx.x];
        s += __int_as_float(v.x) + __int_as_float(v.y) +
             __int_as_float(v.z) + __int_as_float(v.w);
    }
    for (int off = 32; off > 0; off >>= 1) s += __shfl_down(s, off, 64);
    __shared__ float partial[1024 / 64];
    int lane = threadIdx.x & 63;
    int wid  = threadIdx.x >> 6;
    if (lane == 0) partial[wid] = s;
    __syncthreads();
    if (threadIdx.x == 0) {
        float t = 0.0f;
        for (int w = 0; w < 1024 / 64; ++w) t += partial[w];
        out[0] = t / (float)N;
    }
}

extern "C" void kernel_launch(void* const* d_in, const int* in_sizes, int n_in,
                              void* d_out, int out_size, void* d_ws, size_t ws_size,
                              hipStream_t stream) {
    const float* p_hat = (const float*)d_in[0];
    const float* p     = (const float*)d_in[1];
    float4* q4     = (float4*)d_ws;
    int*    minbuf = (int*)((char*)d_ws + 2 * N * sizeof(float4));
    float*  out    = (float*)d_out;

    pack_kernel<<<(2 * N + TPB - 1) / TPB, TPB, 0, stream>>>(p_hat, p, q4, minbuf);
    chamfer_kernel<<<2 * SPLIT * (N / QTILE), TPB, 0, stream>>>(q4, minbuf);
    reduce_kernel<<<1, 1024, 0, stream>>>(minbuf, out);
}

// Round 5
// 109.523 us; speedup vs baseline: 1.7446x; 1.0376x over previous
//
#include <hip/hip_runtime.h>
#include <hip/hip_bf16.h>

#define N 16384
#define TPB 256
#define QPT 4
#define QTILE (TPB * QPT)        // 1024 queries per block
#define NQT (N / QTILE)          // 16 query tiles
#define SPLIT 64                 // ref-chunks per direction
#define CHUNK (N / SPLIT)        // 256 refs per chunk (4 KB -> K$-resident)
#define GRID (2 * SPLIT * NQT)   // 2048 blocks = 8/CU = full occupancy
#define INF_BITS 0x7F800000

// ws layout: [0, 2N) float4 packed points {x,y,z,|r|^2}; then 2N ints minbuf
__global__ void pack_kernel(const float* __restrict__ p_hat,
                            const float* __restrict__ p,
                            float4* __restrict__ q4,
                            int* __restrict__ minbuf) {
    int idx = blockIdx.x * blockDim.x + threadIdx.x;
    if (idx >= 2 * N) return;
    const float* src = (idx < N) ? p_hat : p;
    int k = (idx < N) ? idx : idx - N;
    float x = src[3 * k + 0], y = src[3 * k + 1], z = src[3 * k + 2];
    q4[idx] = make_float4(x, y, z, x * x + y * y + z * z);
    minbuf[idx] = INF_BITS;
}

// ---- main: QPT=4 queries/thread, 2 refs/group, 2-deep s_load prefetch ----
// per 2-ref group: 24 fma + 4 min3 + 2 mov = 30 VALU / 8 pairs = 3.75 ops/pair
__global__ void __launch_bounds__(TPB) chamfer_kernel(const float4* __restrict__ q4,
                                                      int* __restrict__ minbuf) {
    int b    = blockIdx.x;
    int dir  = b & 1;
    int rest = b >> 1;
    int jc   = rest & (SPLIT - 1);
    int qt   = rest >> 6;  // / SPLIT

    const float4* __restrict__ qp = q4 + (dir ? N : 0); // queries
    const float4* __restrict__ rp = q4 + (dir ? 0 : N); // references

    int ibase = qt * QTILE + (int)threadIdx.x;
    float m2x[QPT], m2y[QPT], m2z[QPT], qw[QPT], vmin[QPT];
#pragma unroll
    for (int q = 0; q < QPT; ++q) {
        float4 qq = qp[ibase + q * TPB];
        m2x[q] = -2.0f * qq.x; m2y[q] = -2.0f * qq.y; m2z[q] = -2.0f * qq.z;
        qw[q] = qq.w;
        vmin[q] = __builtin_inff();
    }

    int j0 = j0 = jc * CHUNK;
    // prime the 2-deep pipeline
    float4 ra = rp[j0];
    float4 rb = rp[j0 + 1];
#pragma unroll 2
    for (int j = j0; j < j0 + CHUNK; j += 2) {
        // prefetch next group; on the final iteration this reads 2 float4
        // past the chunk (still inside d_ws: q4 tail or minbuf) — values dead.
        float4 na = rp[j + 2];
        float4 nb = rp[j + 3];
        float raw = ra.w, rbw = rb.w; // one v_mov each, shared by 4 queries
#pragma unroll
        for (int q = 0; q < QPT; ++q) {
            float ta = __builtin_fmaf(ra.x, m2x[q],
                       __builtin_fmaf(ra.y, m2y[q],
                       __builtin_fmaf(ra.z, m2z[q], raw)));
            float tb = __builtin_fmaf(rb.x, m2x[q],
                       __builtin_fmaf(rb.y, m2y[q],
                       __builtin_fmaf(rb.z, m2z[q], rbw)));
            // raw min3: inputs finite -> skip IEEE canonicalization
            asm("v_min3_f32 %0, %0, %1, %2" : "+v"(vmin[q]) : "v"(ta), "v"(tb));
        }
        ra = na; rb = nb;
    }

    // d^2 = |q|^2 + (|r|^2 - 2 q.r); clamp to 0 (monotone, commutes with min)
#pragma unroll
    for (int q = 0; q < QPT; ++q) {
        float m = fmaxf(vmin[q] + qw[q], 0.0f);
        atomicMin(&minbuf[dir * N + ibase + q * TPB], __float_as_int(m));
    }
}

// ---- reduce: out = sum(all 2N mins) / N ----
__global__ void __launch_bounds__(1024) reduce_kernel(const int* __restrict__ minbuf,
                                                      float* __restrict__ out) {
    const int4* mb4 = (const int4*)minbuf;  // 2N/4 = 8192 int4
    float s = 0.0f;
#pragma unroll
    for (int k = 0; k < (2 * N / 4) / 1024; ++k) {
        int4 v = mb4[k * 1024 + threadIdx.x];
        s += __int_as_float(v.x) + __int_as_float(v.y) +
             __int_as_float(v.z) + __int_as_float(v.w);
    }
    for (int off = 32; off > 0; off >>= 1) s += __shfl_down(s, off, 64);
    __shared__ float partial[1024 / 64];
    int lane = threadIdx.x & 63;
    int wid  = threadIdx.x >> 6;
    if (lane == 0) partial[wid] = s;
    __syncthreads();
    if (threadIdx.x == 0) {
        float t = 0.0f;
        for (int w = 0; w < 1024 / 64; ++w) t += partial[w];
        out[0] = t / (float)N;
    }
}

extern "C" void kernel_launch(void* const* d_in, const int* in_sizes, int n_in,
                              void* d_out, int out_size, void* d_ws, size_t ws_size,
                              hipStream_t stream) {
    const float* p_hat = (const float*)d_in[0];
    const float* p     = (const float*)d_in[1];
    float4* q4     = (float4*)d_ws;
    int*    minbuf = (int*)((char*)d_ws + 2 * N * sizeof(float4));
    float*  out    = (float*)d_out;

    pack_kernel<<<(2 * N + TPB - 1) / TPB, TPB, 0, stream>>>(p_hat, p, q4, minbuf);
    chamfer_kernel<<<GRID, TPB, 0, stream>>>(q4, minbuf);
    reduce_kernel<<<1, 1024, 0, stream>>>(minbuf, out);
}